// Round 3
// baseline (510.831 us; speedup 1.0000x reference)
//
#include <hip/hip_runtime.h>
#include <hip/hip_cooperative_groups.h>
#include <stdint.h>

namespace cg = cooperative_groups;

#define HIST_BINS 65536
#define SORT_CAP 4096
#define TPB 256
#define GRID 256

// ws layout (32-bit words unless noted):
//   hist[3][65536]            @ word 0
//   cnt[3]                    @ word 196608
//   thr[3]                    @ word 196612  (pad to 196616)
//   cand[3][SORT_CAP] (u64)   @ byte 786464
//   idx[3][K]                 @ byte 786464 + 98304 = 884768

__device__ __forceinline__ unsigned fkey(float f) {
    unsigned u = __float_as_uint(f);
    return (u & 0x80000000u) ? ~u : (u | 0x80000000u);  // monotone: bigger float -> bigger key
}

__global__ void __launch_bounds__(TPB, 2) fused_kernel(
    const float* __restrict__ h, const float* __restrict__ A,
    const float* __restrict__ W, const float* __restrict__ b,
    const int* __restrict__ bag, float* __restrict__ out,
    unsigned* __restrict__ ws, int N, int D, int K)
{
    cg::grid_group grid = cg::this_grid();
    __shared__ __align__(16) unsigned long long s[SORT_CAP + 2];
    __shared__ unsigned wsum[4];

    unsigned*           hist = ws;
    unsigned*           cnt  = ws + 3 * HIST_BINS;
    unsigned*           thr  = ws + 3 * HIST_BINS + 4;
    unsigned long long* cand = (unsigned long long*)(ws + 3 * HIST_BINS + 8);
    int*                idx  = (int*)(cand + 3 * SORT_CAP);

    const int tid = blockIdx.x * blockDim.x + threadIdx.x;
    const int nthr = gridDim.x * blockDim.x;
    const int c_in = bag[0] & 1;
    const int M = 3 * K;

    // ---- phase 0: zero hist + cnt ----
    for (int i = tid; i < 3 * HIST_BINS + 4; i += nthr) ws[i] = 0u;
    grid.sync();

    // ---- phase 1: 16-bit-prefix histogram of the 3 selection keys ----
    for (int i = tid; i < N; i += nthr) {
        float2 a = ((const float2*)A)[i];
        float aI = c_in ? a.y : a.x;
        float aO = c_in ? a.x : a.y;
        unsigned k0 = fkey(aI);
        atomicAdd(&hist[0 * HIST_BINS + (k0 >> 16)], 1u);
        atomicAdd(&hist[1 * HIST_BINS + ((~k0) >> 16)], 1u);   // fkey(-x) == ~fkey(x)
        atomicAdd(&hist[2 * HIST_BINS + (fkey(aO) >> 16)], 1u);
    }
    grid.sync();

    // ---- phase 2: threshold bin per selection (blocks 0..2) ----
    // T = bin containing the (N-K)-th element in ascending cumulative order.
    if (blockIdx.x < 3) {
        int sel = blockIdx.x;
        const uint4* hv = (const uint4*)(hist + sel * HIST_BINS);
        int t = threadIdx.x;
        int lane = t & 63, wid = t >> 6;
        int base4 = t * 64;                     // 64 uint4 = 256 bins per thread
        unsigned mySum = 0;
        #pragma unroll 8
        for (int v = 0; v < 64; ++v) {
            uint4 q = hv[base4 + v];
            mySum += q.x + q.y + q.z + q.w;
        }
        unsigned x = mySum;                     // inclusive wave scan
        #pragma unroll
        for (int off = 1; off < 64; off <<= 1) {
            unsigned v = __shfl_up(x, off, 64);
            if (lane >= off) x += v;
        }
        if (lane == 63) wsum[wid] = x;
        __syncthreads();
        if (t == 0) {
            unsigned run = 0;
            #pragma unroll
            for (int k = 0; k < 4; ++k) { unsigned v = wsum[k]; wsum[k] = run; run += v; }
        }
        __syncthreads();
        unsigned cum = wsum[wid] + x - mySum;   // exclusive prefix of this thread's chunk
        unsigned S = (unsigned)(N - K);
        if (cum <= S && cum + mySum > S) {
            for (int v = 0; v < 64; ++v) {
                uint4 q = hv[base4 + v];        // L1-hot reload
                unsigned a4[4] = {q.x, q.y, q.z, q.w};
                #pragma unroll
                for (int j = 0; j < 4; ++j) {
                    unsigned c2 = cum + a4[j];
                    if (cum <= S && c2 > S) thr[sel] = (unsigned)(t * 256 + v * 4 + j);
                    cum = c2;
                }
            }
        }
    }
    grid.sync();

    // ---- phase 3: compact candidates (key16 >= thr) as (key<<32)|~idx ----
    {
        unsigned t0 = thr[0], t1 = thr[1], t2 = thr[2];
        for (int i = tid; i < N; i += nthr) {
            float2 a = ((const float2*)A)[i];
            float aI = c_in ? a.y : a.x;
            float aO = c_in ? a.x : a.y;
            unsigned k0 = fkey(aI), k1 = ~k0, k2 = fkey(aO);
            if ((k0 >> 16) >= t0) {
                unsigned p = atomicAdd(&cnt[0], 1u);
                if (p < SORT_CAP) cand[0 * SORT_CAP + p] = ((unsigned long long)k0 << 32) | (unsigned)(~i);
            }
            if ((k1 >> 16) >= t1) {
                unsigned p = atomicAdd(&cnt[1], 1u);
                if (p < SORT_CAP) cand[1 * SORT_CAP + p] = ((unsigned long long)k1 << 32) | (unsigned)(~i);
            }
            if ((k2 >> 16) >= t2) {
                unsigned p = atomicAdd(&cnt[2], 1u);
                if (p < SORT_CAP) cand[2 * SORT_CAP + p] = ((unsigned long long)k2 << 32) | (unsigned)(~i);
            }
        }
    }
    grid.sync();

    // ---- phase 4: exact rank-by-count, blocks 0..47 (16 per selection) ----
    // one candidate per thread (16*256 = SORT_CAP); inner loop = b128 LDS broadcast
    if (blockIdx.x < 48) {
        int sel = blockIdx.x >> 4;
        unsigned part = blockIdx.x & 15;
        unsigned C = cnt[sel];
        if (C > SORT_CAP) C = SORT_CAP;
        const unsigned long long* c = cand + sel * SORT_CAP;
        for (unsigned j = threadIdx.x; j < C; j += TPB) s[j] = c[j];
        if (threadIdx.x == 0 && (C & 1)) s[C] = 0ull;   // pad for pair reads
        __syncthreads();
        unsigned i = part * TPB + threadIdx.x;
        if (i < C) {
            unsigned long long me = s[i];
            unsigned r = 0;
            unsigned Ce = (C + 1) & ~1u;
            for (unsigned j = 0; j < Ce; j += 2) {
                ulonglong2 p = *(const ulonglong2*)&s[j];
                r += (p.x > me) + (p.y > me);
            }
            if (r < (unsigned)K) idx[sel * K + (int)r] = (int)(~(unsigned)me);
        }
    }
    grid.sync();

    // ---- phase 5: gather + GEMV + softmax, one wave per output row ----
    {
        int gw = tid >> 6;
        int nw = nthr >> 6;
        int lane = tid & 63;
        float b0 = b[0], b1 = b[1];
        for (int r = gw; r < M; r += nw) {
            int src = idx[r];
            const float* row = h + (long long)src * D;
            float acc0 = 0.f, acc1 = 0.f;
            for (int d = lane * 8; d < D; d += 512) {
                float4 v0 = *(const float4*)(row + d);
                float4 v1 = *(const float4*)(row + d + 4);
                float4 w0 = *(const float4*)(W + 2 * d);
                float4 w1 = *(const float4*)(W + 2 * d + 4);
                float4 w2 = *(const float4*)(W + 2 * d + 8);
                float4 w3 = *(const float4*)(W + 2 * d + 12);
                acc0 += v0.x * w0.x + v0.y * w0.z + v0.z * w1.x + v0.w * w1.z
                      + v1.x * w2.x + v1.y * w2.z + v1.z * w3.x + v1.w * w3.z;
                acc1 += v0.x * w0.y + v0.y * w0.w + v0.z * w1.y + v0.w * w1.w
                      + v1.x * w2.y + v1.y * w2.w + v1.z * w3.y + v1.w * w3.w;
            }
            #pragma unroll
            for (int off = 32; off > 0; off >>= 1) {
                acc0 += __shfl_down(acc0, off, 64);
                acc1 += __shfl_down(acc1, off, 64);
            }
            if (lane == 0) {
                float z0 = acc0 + b0;
                float z1 = acc1 + b1;
                float m = fmaxf(z0, z1);
                float e0 = __expf(z0 - m), e1 = __expf(z1 - m);
                float inv = 1.0f / (e0 + e1);
                out[r] = (r < K) ? 1.0f : 0.0f;            // labels
                out[M + 2 * r]         = z0;               // logits_unnorm
                out[M + 2 * r + 1]     = z1;
                out[3 * M + 2 * r]     = e0 * inv;         // softmax
                out[3 * M + 2 * r + 1] = e1 * inv;
            }
        }
    }
}

extern "C" void kernel_launch(void* const* d_in, const int* in_sizes, int n_in,
                              void* d_out, int out_size, void* d_ws, size_t ws_size,
                              hipStream_t stream) {
    const float* h   = (const float*)d_in[0];
    const float* A   = (const float*)d_in[1];
    const float* W   = (const float*)d_in[2];
    const float* b   = (const float*)d_in[3];
    const int*   bag = (const int*)d_in[4];
    float* out = (float*)d_out;
    unsigned* ws = (unsigned*)d_ws;

    int N = in_sizes[1] / 2;          // A is (N,1,2)
    int D = in_sizes[0] / N;          // h is (N,1,D)
    int K = (int)(0.02 * N);          // matches Python int(TOP_K_PERCENT * N)
    if (K == 0) K = 8;

    void* args[] = { (void*)&h, (void*)&A, (void*)&W, (void*)&b, (void*)&bag,
                     (void*)&out, (void*)&ws, (void*)&N, (void*)&D, (void*)&K };
    hipLaunchCooperativeKernel((const void*)fused_kernel, dim3(GRID), dim3(TPB),
                               args, 0, stream);
}